// Round 14
// baseline (218.980 us; speedup 1.0000x reference)
//
#include <hip/hip_runtime.h>
#include <stdint.h>

// VQ-VAE vector quantizer — fp32, NCHW input [64,64,32,32], emb [1024,64].
// r30b = resubmit of r30 (R13 bench was an infra failure: container died,
// no compile/correctness verdict). R10 (109.4us best) + sweeps' E/C
// prefetch deepened 2 -> 4 (rotating 4 named buffer sets, rolled unroll-1
// loop over 4 chunks/iter). Rationale: R12 proved sweep MFMAs are off the
// critical path (70% MFMA removal = no wall change) -> sweeps are
// E-load-latency-bound; depth-2 slack (~140cy) < L2 latency (~200-250cy);
// depth-4 slack ~280cy covers it. Sweep-2's first 4 chunks preload BEFORE
// the threshold barrier (threshold-independent; drained under the reduce
// phase). No full unroll (R11 spill lesson), no loop-carried MFMA-loop
// state (R7 lesson). Macro temps renamed rt0/rt1/rtc (defensive, no
// semantic change). Everything else byte-identical to R10.
constexpr int KCODES = 1024;
constexpr int DDIM   = 64;
constexpr int HW     = 1024;
constexpr int NPTS   = 65536;
constexpr int PPB    = 64;            // points per block
constexpr int NBLK   = NPTS / PPB;    // 1024

constexpr int OUT_IDX  = 4194304;
constexpr int OUT_LOSS = 4259840;
constexpr int OUT_NLL  = 4259841;

// ws 32-bit-unit offsets
constexpr int WS_MAXC  = 0;       // 16 f  : per-init-block max C
constexpr int WS_C     = 16;      // 1024 f: exact np C_k
constexpr int WS_E     = 2048;    // 32768 u32: SWIZZLED bf16-E (64 chunks x 2KB)
constexpr int WS_PART  = 34816;   // 1024 f: per-block loss partials

typedef __attribute__((ext_vector_type(8))) short short8v;
typedef __attribute__((ext_vector_type(4))) float float4v;

__device__ __forceinline__ uint16_t f2bf(float f) {   // RNE fp32->bf16
    uint32_t u = __float_as_uint(f);
    return (uint16_t)((u + 0x7fffu + ((u >> 16) & 1u)) >> 16);
}
__device__ __forceinline__ uint32_t pack2bf(float a, float b) {
    return (uint32_t)f2bf(a) | ((uint32_t)f2bf(b) << 16);
}

__device__ __forceinline__ float np_pairwise_sumsq64(const float* a) {
    float r[8];
    #pragma unroll
    for (int j = 0; j < 8; ++j) r[j] = __fmul_rn(a[j], a[j]);
    #pragma unroll
    for (int i = 8; i < 64; i += 8)
        #pragma unroll
        for (int j = 0; j < 8; ++j)
            r[j] = __fadd_rn(r[j], __fmul_rn(a[i + j], a[i + j]));
    return __fadd_rn(__fadd_rn(__fadd_rn(r[0], r[1]), __fadd_rn(r[2], r[3])),
                     __fadd_rn(__fadd_rn(r[4], r[5]), __fadd_rn(r[6], r[7])));
}

// 16 blocks x 64 threads: code k = blockIdx*64 + tid. Writes SWIZZLED E.
__global__ __launch_bounds__(64) void vq_init(const float* __restrict__ emb,
                                              float* __restrict__ ws) {
    const int k = blockIdx.x * 64 + threadIdx.x;
    float row[DDIM];
    const float4* src = (const float4*)(emb + (size_t)k * DDIM);
    #pragma unroll
    for (int j = 0; j < 16; ++j) ((float4*)row)[j] = src[j];
    float C = np_pairwise_sumsq64(row);
    ws[WS_C + k] = C;
    {
        const int c = k >> 4, col = k & 15;
        uint32_t* eb = (uint32_t*)ws + WS_E + c * 512;   // chunk base (u32)
        #pragma unroll
        for (int q = 0; q < 4; ++q) {
            uint32_t* d0 = eb + (q * 16 + col) * 4;          // b0 plane
            uint32_t* d1 = eb + 256 + (q * 16 + col) * 4;    // b1 plane
            #pragma unroll
            for (int j = 0; j < 4; ++j) {
                d0[j] = pack2bf(row[q * 8 + 2 * j],      row[q * 8 + 2 * j + 1]);
                d1[j] = pack2bf(row[32 + q * 8 + 2 * j], row[32 + q * 8 + 2 * j + 1]);
            }
        }
    }
    float m = C;
    #pragma unroll
    for (int off = 32; off > 0; off >>= 1) m = fmaxf(m, __shfl_down(m, off, 64));
    if (threadIdx.x == 0) ws[WS_MAXC + blockIdx.x] = m;
}

// sweep-1 chunk body: 8 MFMAs + per-g running max
#define S1_CHUNK(E0, E1, CIV)                                                 \
    {                                                                         \
        float4v ci = {(CIV)[0] * -0.5f, (CIV)[1] * -0.5f,                     \
                      (CIV)[2] * -0.5f, (CIV)[3] * -0.5f};                    \
        _Pragma("unroll")                                                     \
        for (int g = 0; g < 4; ++g) {                                         \
            float4v acc = ci;                                                 \
            acc = __builtin_amdgcn_mfma_f32_16x16x32_bf16(E0, a[g][0], acc, 0, 0, 0); \
            acc = __builtin_amdgcn_mfma_f32_16x16x32_bf16(E1, a[g][1], acc, 0, 0, 0); \
            gmax[g] = fmaxf(gmax[g],                                          \
                fmaxf(fmaxf(acc[0], acc[1]), fmaxf(acc[2], acc[3])));         \
        }                                                                     \
    }

// sweep-2 chunk body: 8 MFMAs + fixed-threshold candidate push (R10 logic)
#define S2_CHUNK(E0, E1, CIV, CHUNK)                                          \
    {                                                                         \
        float4v ci = {(CIV)[0] * -0.5f, (CIV)[1] * -0.5f,                     \
                      (CIV)[2] * -0.5f, (CIV)[3] * -0.5f};                    \
        const int kb = k0 + (CHUNK) * 16 + quad * 4;                          \
        _Pragma("unroll")                                                     \
        for (int g = 0; g < 4; ++g) {                                         \
            float4v acc = ci;                                                 \
            acc = __builtin_amdgcn_mfma_f32_16x16x32_bf16(E0, a[g][0], acc, 0, 0, 0); \
            acc = __builtin_amdgcn_mfma_f32_16x16x32_bf16(E1, a[g][1], acc, 0, 0, 0); \
            float m4 = fmaxf(fmaxf(acc[0], acc[1]), fmaxf(acc[2], acc[3]));   \
            if (__any(m4 >= thrg[g])) {                                       \
                _Pragma("unroll")                                             \
                for (int r = 0; r < 4; ++r) {                                 \
                    if (acc[r] >= thrg[g]) {                                  \
                        if (cnt[g] < 4)                                       \
                            lst[g] |= (unsigned long long)(unsigned)(kb + r)  \
                                      << (cnt[g] << 4);                       \
                        ++cnt[g];                                             \
                    }                                                         \
                }                                                             \
            }                                                                 \
        }                                                                     \
    }

// rotate: consume buffer into temps, refill with chunk NEXT (if valid)
#define ROT4(EX0, EX1, CX, NEXT)                                              \
    short8v rt0 = EX0, rt1 = EX1; float4v rtc = CX;                           \
    if ((NEXT) < 16) {                                                        \
        const char* er = Ew + (size_t)(NEXT) * 2048;                          \
        EX0 = *(const short8v*)(er);                                          \
        EX1 = *(const short8v*)(er + 1024);                                   \
        CX  = Cq[(NEXT) * 4 + quad];                                          \
    }

__global__ __launch_bounds__(256, 4) void vq_main(
        const float* __restrict__ inp, const float* __restrict__ emb,
        float* __restrict__ ws, float* __restrict__ out)
{
    __shared__ float    sAp[PPB][4];    // pairwise partials (r2j + r2j+1)
    __shared__ float    sA[PPB];
    __shared__ float    sPart[4][PPB];
    __shared__ float    sThr[PPB];
    __shared__ unsigned long long sCandL[16][PPB];  // [wave*4+quad][point]
    __shared__ int      sCntL[16][PPB];
    __shared__ float    sResB[4][PPB];  // per-wave partial min distance
    __shared__ int      sResW[4][PPB];  // per-wave partial argmin
    __shared__ int      sWin[PPB];
    __shared__ float    sred[4];

    const int tid  = threadIdx.x;
    const int lane = tid & 63;
    const int wave = tid >> 6;          // = code quarter
    const int col  = lane & 15;         // = POINT within 16-group (swapped layout)
    const int quad = lane >> 4;         // = code sub-quad (rows quad*4+r)
    const int base = blockIdx.x * PPB;
    const int b    = base >> 10;
    const int hw0  = base & 1023;

    // ---- prologue: exact-A partials, 4 threads per point (bit-exact tree
    //      split of np pairwise: this thread computes r_{2j}+r_{2j+1}) -------
    {
        const int pp = tid >> 2;            // point
        const int jj = (tid & 3) * 2;       // r-pair base
        const float* xin = inp + (size_t)b * DDIM * HW + (hw0 + pp);
        float r0, r1;
        {
            float v0 = xin[(size_t)jj * HW];
            float v1 = xin[(size_t)(jj + 1) * HW];
            r0 = __fmul_rn(v0, v0);
            r1 = __fmul_rn(v1, v1);
        }
        #pragma unroll
        for (int i = 8; i < 64; i += 8) {
            float v0 = xin[(size_t)(i + jj) * HW];
            float v1 = xin[(size_t)(i + jj + 1) * HW];
            r0 = __fadd_rn(r0, __fmul_rn(v0, v0));
            r1 = __fadd_rn(r1, __fmul_rn(v1, v1));
        }
        sAp[pp][tid & 3] = __fadd_rn(r0, r1);
    }

    // ---- X-fragments for 4 row-groups (unchanged; reused as MFMA B-op) ----
    short8v a[4][2];
    #pragma unroll
    for (int g = 0; g < 4; ++g) {
        const float* xp = inp + (size_t)b * DDIM * HW + (hw0 + g * 16 + col);
        short8v t0, t1;
        #pragma unroll
        for (int j = 0; j < 8; ++j) {
            t0[j] = (short)f2bf(xp[(size_t)(quad * 8 + j) * HW]);
            t1[j] = (short)f2bf(xp[(size_t)(32 + quad * 8 + j) * HW]);
        }
        a[g][0] = t0; a[g][1] = t1;
    }

    // swizzled E: lane reads its 16B at chunk*2048 + plane*1024 + lane*16 —
    // contiguous 1KB per wave-load; lane&15 indexes CODE -> valid A-fragment.
    const char* Eb = (const char*)((const uint32_t*)ws + WS_E);
    const char* Ew = Eb + (size_t)wave * 16 * 2048 + (size_t)lane * 16;
    const float* Cw = ws + WS_C;
    const int k0 = wave * 256;
    const float4v* Cq = (const float4v*)(ws + WS_C + k0);   // 16B-aligned

    // ---- sweep 1: per-point score-max, depth-4 rotating prefetch -----------
    float gmax[4] = {-3.0e38f, -3.0e38f, -3.0e38f, -3.0e38f};
    {
        short8v eA0 = *(const short8v*)(Ew);
        short8v eA1 = *(const short8v*)(Ew + 1024);
        short8v eB0 = *(const short8v*)(Ew + 2048);
        short8v eB1 = *(const short8v*)(Ew + 3072);
        short8v eC0 = *(const short8v*)(Ew + 4096);
        short8v eC1 = *(const short8v*)(Ew + 5120);
        short8v eD0 = *(const short8v*)(Ew + 6144);
        short8v eD1 = *(const short8v*)(Ew + 7168);
        float4v cA = Cq[quad];
        float4v cB = Cq[4 + quad];
        float4v cC = Cq[8 + quad];
        float4v cD = Cq[12 + quad];
        #pragma unroll 1
        for (int c4 = 0; c4 < 16; c4 += 4) {
            { ROT4(eA0, eA1, cA, c4 + 4) S1_CHUNK(rt0, rt1, rtc) }
            { ROT4(eB0, eB1, cB, c4 + 5) S1_CHUNK(rt0, rt1, rtc) }
            { ROT4(eC0, eC1, cC, c4 + 6) S1_CHUNK(rt0, rt1, rtc) }
            { ROT4(eD0, eD1, cD, c4 + 7) S1_CHUNK(rt0, rt1, rtc) }
        }
    }
    // cross-quad reduce: 2 shuffles
    #pragma unroll
    for (int g = 0; g < 4; ++g) {
        float m = gmax[g];
        m = fmaxf(m, __shfl_xor(m, 16, 64));
        m = fmaxf(m, __shfl_xor(m, 32, 64));
        if (quad == 0) sPart[wave][g * 16 + col] = m;
    }

    // ---- preload sweep-2's first 4 chunks BEFORE the threshold barrier -----
    //      (threshold-independent; latency drains under reduce+threshold)
    short8v fA0 = *(const short8v*)(Ew);
    short8v fA1 = *(const short8v*)(Ew + 1024);
    short8v fB0 = *(const short8v*)(Ew + 2048);
    short8v fB1 = *(const short8v*)(Ew + 3072);
    short8v fC0 = *(const short8v*)(Ew + 4096);
    short8v fC1 = *(const short8v*)(Ew + 5120);
    short8v fD0 = *(const short8v*)(Ew + 6144);
    short8v fD1 = *(const short8v*)(Ew + 7168);
    float4v dA = Cq[quad];
    float4v dB = Cq[4 + quad];
    float4v dC = Cq[8 + quad];
    float4v dD = Cq[12 + quad];
    __syncthreads();

    // ---- per-point threshold (also combine exact-A partials, exact tree) ---
    if (tid < PPB) {
        float A = __fadd_rn(__fadd_rn(sAp[tid][0], sAp[tid][1]),
                            __fadd_rn(sAp[tid][2], sAp[tid][3]));
        sA[tid] = A;
        float gm = fmaxf(fmaxf(sPart[0][tid], sPart[1][tid]),
                         fmaxf(sPart[2][tid], sPart[3][tid]));
        float mc = ws[WS_MAXC];
        #pragma unroll
        for (int j = 1; j < 16; ++j) mc = fmaxf(mc, ws[WS_MAXC + j]);
        sThr[tid] = gm - (0.015625f * sqrtf(A) * sqrtf(mc) + 6e-5f);
    }
    __syncthreads();

    float thrg[4];
    #pragma unroll
    for (int g = 0; g < 4; ++g) thrg[g] = sThr[g * 16 + col];

    // ---- sweep 2: candidates via per-lane u64 lists, depth-4 prefetch ------
    unsigned long long lst[4] = {0ull, 0ull, 0ull, 0ull};
    int cnt[4] = {0, 0, 0, 0};
    {
        #pragma unroll 1
        for (int c4 = 0; c4 < 16; c4 += 4) {
            { ROT4(fA0, fA1, dA, c4 + 4) S2_CHUNK(rt0, rt1, rtc, c4) }
            { ROT4(fB0, fB1, dB, c4 + 5) S2_CHUNK(rt0, rt1, rtc, c4 + 1) }
            { ROT4(fC0, fC1, dC, c4 + 6) S2_CHUNK(rt0, rt1, rtc, c4 + 2) }
            { ROT4(fD0, fD1, dD, c4 + 7) S2_CHUNK(rt0, rt1, rtc, c4 + 3) }
        }
    }
    {
        const int wq = wave * 4 + quad;
        #pragma unroll
        for (int g = 0; g < 4; ++g) {
            sCandL[wq][g * 16 + col] = lst[g];
            sCntL[wq][g * 16 + col]  = cnt[g];
        }
    }
    __syncthreads();

    // ---- rescue phase A: each wave exact-evals ITS candidate quads ---------
    {
        const int p = lane;
        int tot = 0, cmax = 0, mycnt = 0;
        #pragma unroll
        for (int wq = 0; wq < 16; ++wq) {
            int c = sCntL[wq][p];
            tot += c;
            cmax = c > cmax ? c : cmax;
            if ((wq >> 2) == wave) mycnt += c;
        }
        if (tot >= 2 && cmax <= 4) {
            float bd = 3.0e38f; int win = KCODES - 1;
            if (mycnt > 0) {
                const float* xin = inp + (size_t)b * DDIM * HW + (hw0 + p);
                float x[DDIM];
                #pragma unroll
                for (int d = 0; d < DDIM; ++d) x[d] = xin[(size_t)d * HW];
                const float A = sA[p];
                #pragma unroll 1
                for (int q = 0; q < 4; ++q) {
                    const int wq = wave * 4 + q;
                    int c = sCntL[wq][p];
                    unsigned long long L = sCandL[wq][p];
                    #pragma unroll 1
                    for (int i = 0; i < c; ++i) {       // ascending k order
                        int k = (int)(L & 0xffffu);
                        L >>= 16;
                        float e[DDIM];
                        const float4* e4 = (const float4*)(emb + (size_t)k * DDIM);
                        #pragma unroll
                        for (int j = 0; j < 16; ++j) ((float4*)e)[j] = e4[j];
                        float g = 0.f;
                        #pragma unroll
                        for (int d = 0; d < DDIM; ++d) g = fmaf(x[d], e[d], g);
                        float dd = __fadd_rn(__fsub_rn(A, __fmul_rn(2.0f, g)), Cw[k]);
                        if (dd < bd || (dd == bd && k < win)) { bd = dd; win = k; }
                    }
                }
            }
            sResB[wave][p] = bd;
            sResW[wave][p] = win;
        }
    }
    __syncthreads();

    // ---- rescue phase B: combine (tid<64); fast/fallback paths unchanged ---
    if (tid < PPB) {
        const int p = tid, n = base + p;
        int tot = 0, cmax = 0;
        #pragma unroll
        for (int wq = 0; wq < 16; ++wq) {
            int c = sCntL[wq][p];
            tot += c;
            cmax = c > cmax ? c : cmax;
        }
        int win;
        if (tot == 1) {
            win = 0;
            #pragma unroll
            for (int wq = 0; wq < 16; ++wq)
                if (sCntL[wq][p]) win = (int)(sCandL[wq][p] & 0xffffu);
        } else if (cmax <= 4) {
            float bd = 3.0e38f; win = KCODES - 1;
            #pragma unroll
            for (int w = 0; w < 4; ++w) {       // ascending k-range order
                float dw = sResB[w][p];
                int   ww = sResW[w][p];
                if (dw < bd || (dw == bd && ww < win)) { bd = dw; win = ww; }
            }
        } else {                                    // overflow safety
            const float* xin = inp + (size_t)b * DDIM * HW + (hw0 + p);
            float x[DDIM];
            #pragma unroll
            for (int d = 0; d < DDIM; ++d) x[d] = xin[(size_t)d * HW];
            const float A = sA[p];
            float bd = 3.0e38f; win = KCODES - 1;
            #pragma unroll 1
            for (int k = 0; k < KCODES; ++k) {
                float e[DDIM];
                const float4* e4 = (const float4*)(emb + (size_t)k * DDIM);
                #pragma unroll
                for (int j = 0; j < 16; ++j) ((float4*)e)[j] = e4[j];
                float g = 0.f;
                #pragma unroll
                for (int d = 0; d < DDIM; ++d) g = fmaf(x[d], e[d], g);
                float dd = __fadd_rn(__fsub_rn(A, __fmul_rn(2.0f, g)), Cw[k]);
                if (dd < bd) { bd = dd; win = k; }
            }
        }
        sWin[p] = win;
        out[OUT_IDX + n] = (float)win;
    }
    __syncthreads();

    // ---- epilogue: quantized NCHW + loss partial (plain store) -------------
    {
        const int pl = tid & 63, qtr = tid >> 6;
        const int win = sWin[pl];
        const int ch0 = qtr * 16;
        float q[16];
        const float4* q4 = (const float4*)(emb + (size_t)win * DDIM + ch0);
        #pragma unroll
        for (int j = 0; j < 4; ++j) ((float4*)q)[j] = q4[j];
        const size_t off = (size_t)b * DDIM * HW + (size_t)ch0 * HW + (hw0 + pl);
        const float* xin2 = inp + off;
        float* orow = out + off;
        float lacc = 0.f;
        #pragma unroll
        for (int j = 0; j < 16; ++j) {
            float xv = xin2[(size_t)j * HW];
            float diff = __fsub_rn(q[j], xv);
            orow[(size_t)j * HW] = __fadd_rn(xv, diff);   // ref's x + (q - x)
            lacc = fmaf(diff, diff, lacc);
        }
        #pragma unroll
        for (int o2 = 32; o2 > 0; o2 >>= 1) lacc += __shfl_down(lacc, o2, 64);
        if (lane == 0) sred[wave] = lacc;
    }
    __syncthreads();
    if (tid == 0)
        ws[WS_PART + blockIdx.x] = sred[0] + sred[1] + sred[2] + sred[3];
}

// 1 block x 256: reduce 1024 partials -> loss; write nll
__global__ __launch_bounds__(256) void vq_fin(const float* __restrict__ ws,
                                              float* __restrict__ out) {
    __shared__ float sred[4];
    const int tid = threadIdx.x;
    float s = 0.f;
    #pragma unroll
    for (int j = 0; j < 4; ++j) s += ws[WS_PART + j * 256 + tid];
    #pragma unroll
    for (int off = 32; off > 0; off >>= 1) s += __shfl_down(s, off, 64);
    if ((tid & 63) == 0) sred[tid >> 6] = s;
    __syncthreads();
    if (tid == 0) {
        float L = sred[0] + sred[1] + sred[2] + sred[3];
        out[OUT_LOSS] = L * (1.25f / 4194304.0f);   // (1+CC)*mean over N*D
        out[OUT_NLL]  = 1.0f;
    }
}

extern "C" void kernel_launch(void* const* d_in, const int* in_sizes, int n_in,
                              void* d_out, int out_size, void* d_ws, size_t ws_size,
                              hipStream_t stream) {
    const float* inp = (const float*)d_in[0];
    const float* emb = (const float*)d_in[1];
    float* out = (float*)d_out;
    float* ws  = (float*)d_ws;

    vq_init<<<16, 64, 0, stream>>>(emb, ws);
    vq_main<<<NBLK, 256, 0, stream>>>(inp, emb, ws, out);
    vq_fin<<<1, 256, 0, stream>>>(ws, out);
}

// Round 15
// 121.855 us; speedup vs baseline: 1.7970x; 1.7970x over previous
//
#include <hip/hip_runtime.h>
#include <stdint.h>

// VQ-VAE vector quantizer — fp32, NCHW input [64,64,32,32], emb [1024,64].
// r31 = R10 (109.4us best) + depth-4 rotating E/C prefetch inside each
// sweep. R14's version spilled (FETCH 97MB): bounds(256,4) drove the
// allocator to a 64-VGPR target and the cross-barrier preload held 48
// VGPRs live across two syncthreads. Fixes: (1) NO cross-barrier preload —
// sweep 2 loads its initial buffers after the threshold read (R10 pattern);
// (2) __launch_bounds__(256,2) — R9 precedent: allocator uses 84+ VGPR
// cleanly, and R8 proved occupancy-insensitivity. Peak live ~95 VGPR.
// Rationale unchanged: R12 proved sweep MFMAs off the critical path ->
// sweeps are E-load-latency-bound; depth-2 slack (~140cy) < L2 latency
// (~200-250cy); depth-4 (~280cy) covers it. No full unroll (R11 lesson),
// no loop-carried MFMA-loop state (R7 lesson). Else byte-identical to R10.
constexpr int KCODES = 1024;
constexpr int DDIM   = 64;
constexpr int HW     = 1024;
constexpr int NPTS   = 65536;
constexpr int PPB    = 64;            // points per block
constexpr int NBLK   = NPTS / PPB;    // 1024

constexpr int OUT_IDX  = 4194304;
constexpr int OUT_LOSS = 4259840;
constexpr int OUT_NLL  = 4259841;

// ws 32-bit-unit offsets
constexpr int WS_MAXC  = 0;       // 16 f  : per-init-block max C
constexpr int WS_C     = 16;      // 1024 f: exact np C_k
constexpr int WS_E     = 2048;    // 32768 u32: SWIZZLED bf16-E (64 chunks x 2KB)
constexpr int WS_PART  = 34816;   // 1024 f: per-block loss partials

typedef __attribute__((ext_vector_type(8))) short short8v;
typedef __attribute__((ext_vector_type(4))) float float4v;

__device__ __forceinline__ uint16_t f2bf(float f) {   // RNE fp32->bf16
    uint32_t u = __float_as_uint(f);
    return (uint16_t)((u + 0x7fffu + ((u >> 16) & 1u)) >> 16);
}
__device__ __forceinline__ uint32_t pack2bf(float a, float b) {
    return (uint32_t)f2bf(a) | ((uint32_t)f2bf(b) << 16);
}

__device__ __forceinline__ float np_pairwise_sumsq64(const float* a) {
    float r[8];
    #pragma unroll
    for (int j = 0; j < 8; ++j) r[j] = __fmul_rn(a[j], a[j]);
    #pragma unroll
    for (int i = 8; i < 64; i += 8)
        #pragma unroll
        for (int j = 0; j < 8; ++j)
            r[j] = __fadd_rn(r[j], __fmul_rn(a[i + j], a[i + j]));
    return __fadd_rn(__fadd_rn(__fadd_rn(r[0], r[1]), __fadd_rn(r[2], r[3])),
                     __fadd_rn(__fadd_rn(r[4], r[5]), __fadd_rn(r[6], r[7])));
}

// 16 blocks x 64 threads: code k = blockIdx*64 + tid. Writes SWIZZLED E.
__global__ __launch_bounds__(64) void vq_init(const float* __restrict__ emb,
                                              float* __restrict__ ws) {
    const int k = blockIdx.x * 64 + threadIdx.x;
    float row[DDIM];
    const float4* src = (const float4*)(emb + (size_t)k * DDIM);
    #pragma unroll
    for (int j = 0; j < 16; ++j) ((float4*)row)[j] = src[j];
    float C = np_pairwise_sumsq64(row);
    ws[WS_C + k] = C;
    {
        const int c = k >> 4, col = k & 15;
        uint32_t* eb = (uint32_t*)ws + WS_E + c * 512;   // chunk base (u32)
        #pragma unroll
        for (int q = 0; q < 4; ++q) {
            uint32_t* d0 = eb + (q * 16 + col) * 4;          // b0 plane
            uint32_t* d1 = eb + 256 + (q * 16 + col) * 4;    // b1 plane
            #pragma unroll
            for (int j = 0; j < 4; ++j) {
                d0[j] = pack2bf(row[q * 8 + 2 * j],      row[q * 8 + 2 * j + 1]);
                d1[j] = pack2bf(row[32 + q * 8 + 2 * j], row[32 + q * 8 + 2 * j + 1]);
            }
        }
    }
    float m = C;
    #pragma unroll
    for (int off = 32; off > 0; off >>= 1) m = fmaxf(m, __shfl_down(m, off, 64));
    if (threadIdx.x == 0) ws[WS_MAXC + blockIdx.x] = m;
}

// sweep-1 chunk body: 8 MFMAs + per-g running max
#define S1_CHUNK(E0, E1, CIV)                                                 \
    {                                                                         \
        float4v ci = {(CIV)[0] * -0.5f, (CIV)[1] * -0.5f,                     \
                      (CIV)[2] * -0.5f, (CIV)[3] * -0.5f};                    \
        _Pragma("unroll")                                                     \
        for (int g = 0; g < 4; ++g) {                                         \
            float4v acc = ci;                                                 \
            acc = __builtin_amdgcn_mfma_f32_16x16x32_bf16(E0, a[g][0], acc, 0, 0, 0); \
            acc = __builtin_amdgcn_mfma_f32_16x16x32_bf16(E1, a[g][1], acc, 0, 0, 0); \
            gmax[g] = fmaxf(gmax[g],                                          \
                fmaxf(fmaxf(acc[0], acc[1]), fmaxf(acc[2], acc[3])));         \
        }                                                                     \
    }

// sweep-2 chunk body: 8 MFMAs + fixed-threshold candidate push (R10 logic)
#define S2_CHUNK(E0, E1, CIV, CHUNK)                                          \
    {                                                                         \
        float4v ci = {(CIV)[0] * -0.5f, (CIV)[1] * -0.5f,                     \
                      (CIV)[2] * -0.5f, (CIV)[3] * -0.5f};                    \
        const int kb = k0 + (CHUNK) * 16 + quad * 4;                          \
        _Pragma("unroll")                                                     \
        for (int g = 0; g < 4; ++g) {                                         \
            float4v acc = ci;                                                 \
            acc = __builtin_amdgcn_mfma_f32_16x16x32_bf16(E0, a[g][0], acc, 0, 0, 0); \
            acc = __builtin_amdgcn_mfma_f32_16x16x32_bf16(E1, a[g][1], acc, 0, 0, 0); \
            float m4 = fmaxf(fmaxf(acc[0], acc[1]), fmaxf(acc[2], acc[3]));   \
            if (__any(m4 >= thrg[g])) {                                       \
                _Pragma("unroll")                                             \
                for (int r = 0; r < 4; ++r) {                                 \
                    if (acc[r] >= thrg[g]) {                                  \
                        if (cnt[g] < 4)                                       \
                            lst[g] |= (unsigned long long)(unsigned)(kb + r)  \
                                      << (cnt[g] << 4);                       \
                        ++cnt[g];                                             \
                    }                                                         \
                }                                                             \
            }                                                                 \
        }                                                                     \
    }

// rotate: consume buffer into temps, refill with chunk NEXT (if valid)
#define ROT4(EX0, EX1, CX, NEXT)                                              \
    short8v rt0 = EX0, rt1 = EX1; float4v rtc = CX;                           \
    if ((NEXT) < 16) {                                                        \
        const char* er = Ew + (size_t)(NEXT) * 2048;                          \
        EX0 = *(const short8v*)(er);                                          \
        EX1 = *(const short8v*)(er + 1024);                                   \
        CX  = Cq[(NEXT) * 4 + quad];                                          \
    }

__global__ __launch_bounds__(256, 2) void vq_main(
        const float* __restrict__ inp, const float* __restrict__ emb,
        float* __restrict__ ws, float* __restrict__ out)
{
    __shared__ float    sAp[PPB][4];    // pairwise partials (r2j + r2j+1)
    __shared__ float    sA[PPB];
    __shared__ float    sPart[4][PPB];
    __shared__ float    sThr[PPB];
    __shared__ unsigned long long sCandL[16][PPB];  // [wave*4+quad][point]
    __shared__ int      sCntL[16][PPB];
    __shared__ float    sResB[4][PPB];  // per-wave partial min distance
    __shared__ int      sResW[4][PPB];  // per-wave partial argmin
    __shared__ int      sWin[PPB];
    __shared__ float    sred[4];

    const int tid  = threadIdx.x;
    const int lane = tid & 63;
    const int wave = tid >> 6;          // = code quarter
    const int col  = lane & 15;         // = POINT within 16-group (swapped layout)
    const int quad = lane >> 4;         // = code sub-quad (rows quad*4+r)
    const int base = blockIdx.x * PPB;
    const int b    = base >> 10;
    const int hw0  = base & 1023;

    // ---- prologue: exact-A partials, 4 threads per point (bit-exact tree
    //      split of np pairwise: this thread computes r_{2j}+r_{2j+1}) -------
    {
        const int pp = tid >> 2;            // point
        const int jj = (tid & 3) * 2;       // r-pair base
        const float* xin = inp + (size_t)b * DDIM * HW + (hw0 + pp);
        float r0, r1;
        {
            float v0 = xin[(size_t)jj * HW];
            float v1 = xin[(size_t)(jj + 1) * HW];
            r0 = __fmul_rn(v0, v0);
            r1 = __fmul_rn(v1, v1);
        }
        #pragma unroll
        for (int i = 8; i < 64; i += 8) {
            float v0 = xin[(size_t)(i + jj) * HW];
            float v1 = xin[(size_t)(i + jj + 1) * HW];
            r0 = __fadd_rn(r0, __fmul_rn(v0, v0));
            r1 = __fadd_rn(r1, __fmul_rn(v1, v1));
        }
        sAp[pp][tid & 3] = __fadd_rn(r0, r1);
    }

    // ---- X-fragments for 4 row-groups (unchanged; reused as MFMA B-op) ----
    short8v a[4][2];
    #pragma unroll
    for (int g = 0; g < 4; ++g) {
        const float* xp = inp + (size_t)b * DDIM * HW + (hw0 + g * 16 + col);
        short8v t0, t1;
        #pragma unroll
        for (int j = 0; j < 8; ++j) {
            t0[j] = (short)f2bf(xp[(size_t)(quad * 8 + j) * HW]);
            t1[j] = (short)f2bf(xp[(size_t)(32 + quad * 8 + j) * HW]);
        }
        a[g][0] = t0; a[g][1] = t1;
    }

    // swizzled E: lane reads its 16B at chunk*2048 + plane*1024 + lane*16 —
    // contiguous 1KB per wave-load; lane&15 indexes CODE -> valid A-fragment.
    const char* Eb = (const char*)((const uint32_t*)ws + WS_E);
    const char* Ew = Eb + (size_t)wave * 16 * 2048 + (size_t)lane * 16;
    const float* Cw = ws + WS_C;
    const int k0 = wave * 256;
    const float4v* Cq = (const float4v*)(ws + WS_C + k0);   // 16B-aligned

    // ---- sweep 1: per-point score-max, depth-4 rotating prefetch -----------
    float gmax[4] = {-3.0e38f, -3.0e38f, -3.0e38f, -3.0e38f};
    {
        short8v eA0 = *(const short8v*)(Ew);
        short8v eA1 = *(const short8v*)(Ew + 1024);
        short8v eB0 = *(const short8v*)(Ew + 2048);
        short8v eB1 = *(const short8v*)(Ew + 3072);
        short8v eC0 = *(const short8v*)(Ew + 4096);
        short8v eC1 = *(const short8v*)(Ew + 5120);
        short8v eD0 = *(const short8v*)(Ew + 6144);
        short8v eD1 = *(const short8v*)(Ew + 7168);
        float4v cA = Cq[quad];
        float4v cB = Cq[4 + quad];
        float4v cC = Cq[8 + quad];
        float4v cD = Cq[12 + quad];
        #pragma unroll 1
        for (int c4 = 0; c4 < 16; c4 += 4) {
            { ROT4(eA0, eA1, cA, c4 + 4) S1_CHUNK(rt0, rt1, rtc) }
            { ROT4(eB0, eB1, cB, c4 + 5) S1_CHUNK(rt0, rt1, rtc) }
            { ROT4(eC0, eC1, cC, c4 + 6) S1_CHUNK(rt0, rt1, rtc) }
            { ROT4(eD0, eD1, cD, c4 + 7) S1_CHUNK(rt0, rt1, rtc) }
        }
    }
    // cross-quad reduce: 2 shuffles
    #pragma unroll
    for (int g = 0; g < 4; ++g) {
        float m = gmax[g];
        m = fmaxf(m, __shfl_xor(m, 16, 64));
        m = fmaxf(m, __shfl_xor(m, 32, 64));
        if (quad == 0) sPart[wave][g * 16 + col] = m;
    }
    __syncthreads();

    // ---- per-point threshold (also combine exact-A partials, exact tree) ---
    if (tid < PPB) {
        float A = __fadd_rn(__fadd_rn(sAp[tid][0], sAp[tid][1]),
                            __fadd_rn(sAp[tid][2], sAp[tid][3]));
        sA[tid] = A;
        float gm = fmaxf(fmaxf(sPart[0][tid], sPart[1][tid]),
                         fmaxf(sPart[2][tid], sPart[3][tid]));
        float mc = ws[WS_MAXC];
        #pragma unroll
        for (int j = 1; j < 16; ++j) mc = fmaxf(mc, ws[WS_MAXC + j]);
        sThr[tid] = gm - (0.015625f * sqrtf(A) * sqrtf(mc) + 6e-5f);
    }
    __syncthreads();

    float thrg[4];
    #pragma unroll
    for (int g = 0; g < 4; ++g) thrg[g] = sThr[g * 16 + col];

    // ---- sweep 2: candidates via per-lane u64 lists, depth-4 prefetch ------
    unsigned long long lst[4] = {0ull, 0ull, 0ull, 0ull};
    int cnt[4] = {0, 0, 0, 0};
    {
        short8v fA0 = *(const short8v*)(Ew);
        short8v fA1 = *(const short8v*)(Ew + 1024);
        short8v fB0 = *(const short8v*)(Ew + 2048);
        short8v fB1 = *(const short8v*)(Ew + 3072);
        short8v fC0 = *(const short8v*)(Ew + 4096);
        short8v fC1 = *(const short8v*)(Ew + 5120);
        short8v fD0 = *(const short8v*)(Ew + 6144);
        short8v fD1 = *(const short8v*)(Ew + 7168);
        float4v dA = Cq[quad];
        float4v dB = Cq[4 + quad];
        float4v dC = Cq[8 + quad];
        float4v dD = Cq[12 + quad];
        #pragma unroll 1
        for (int c4 = 0; c4 < 16; c4 += 4) {
            { ROT4(fA0, fA1, dA, c4 + 4) S2_CHUNK(rt0, rt1, rtc, c4) }
            { ROT4(fB0, fB1, dB, c4 + 5) S2_CHUNK(rt0, rt1, rtc, c4 + 1) }
            { ROT4(fC0, fC1, dC, c4 + 6) S2_CHUNK(rt0, rt1, rtc, c4 + 2) }
            { ROT4(fD0, fD1, dD, c4 + 7) S2_CHUNK(rt0, rt1, rtc, c4 + 3) }
        }
    }
    {
        const int wq = wave * 4 + quad;
        #pragma unroll
        for (int g = 0; g < 4; ++g) {
            sCandL[wq][g * 16 + col] = lst[g];
            sCntL[wq][g * 16 + col]  = cnt[g];
        }
    }
    __syncthreads();

    // ---- rescue phase A: each wave exact-evals ITS candidate quads ---------
    {
        const int p = lane;
        int tot = 0, cmax = 0, mycnt = 0;
        #pragma unroll
        for (int wq = 0; wq < 16; ++wq) {
            int c = sCntL[wq][p];
            tot += c;
            cmax = c > cmax ? c : cmax;
            if ((wq >> 2) == wave) mycnt += c;
        }
        if (tot >= 2 && cmax <= 4) {
            float bd = 3.0e38f; int win = KCODES - 1;
            if (mycnt > 0) {
                const float* xin = inp + (size_t)b * DDIM * HW + (hw0 + p);
                float x[DDIM];
                #pragma unroll
                for (int d = 0; d < DDIM; ++d) x[d] = xin[(size_t)d * HW];
                const float A = sA[p];
                #pragma unroll 1
                for (int q = 0; q < 4; ++q) {
                    const int wq = wave * 4 + q;
                    int c = sCntL[wq][p];
                    unsigned long long L = sCandL[wq][p];
                    #pragma unroll 1
                    for (int i = 0; i < c; ++i) {       // ascending k order
                        int k = (int)(L & 0xffffu);
                        L >>= 16;
                        float e[DDIM];
                        const float4* e4 = (const float4*)(emb + (size_t)k * DDIM);
                        #pragma unroll
                        for (int j = 0; j < 16; ++j) ((float4*)e)[j] = e4[j];
                        float g = 0.f;
                        #pragma unroll
                        for (int d = 0; d < DDIM; ++d) g = fmaf(x[d], e[d], g);
                        float dd = __fadd_rn(__fsub_rn(A, __fmul_rn(2.0f, g)), Cw[k]);
                        if (dd < bd || (dd == bd && k < win)) { bd = dd; win = k; }
                    }
                }
            }
            sResB[wave][p] = bd;
            sResW[wave][p] = win;
        }
    }
    __syncthreads();

    // ---- rescue phase B: combine (tid<64); fast/fallback paths unchanged ---
    if (tid < PPB) {
        const int p = tid, n = base + p;
        int tot = 0, cmax = 0;
        #pragma unroll
        for (int wq = 0; wq < 16; ++wq) {
            int c = sCntL[wq][p];
            tot += c;
            cmax = c > cmax ? c : cmax;
        }
        int win;
        if (tot == 1) {
            win = 0;
            #pragma unroll
            for (int wq = 0; wq < 16; ++wq)
                if (sCntL[wq][p]) win = (int)(sCandL[wq][p] & 0xffffu);
        } else if (cmax <= 4) {
            float bd = 3.0e38f; win = KCODES - 1;
            #pragma unroll
            for (int w = 0; w < 4; ++w) {       // ascending k-range order
                float dw = sResB[w][p];
                int   ww = sResW[w][p];
                if (dw < bd || (dw == bd && ww < win)) { bd = dw; win = ww; }
            }
        } else {                                    // overflow safety
            const float* xin = inp + (size_t)b * DDIM * HW + (hw0 + p);
            float x[DDIM];
            #pragma unroll
            for (int d = 0; d < DDIM; ++d) x[d] = xin[(size_t)d * HW];
            const float A = sA[p];
            float bd = 3.0e38f; win = KCODES - 1;
            #pragma unroll 1
            for (int k = 0; k < KCODES; ++k) {
                float e[DDIM];
                const float4* e4 = (const float4*)(emb + (size_t)k * DDIM);
                #pragma unroll
                for (int j = 0; j < 16; ++j) ((float4*)e)[j] = e4[j];
                float g = 0.f;
                #pragma unroll
                for (int d = 0; d < DDIM; ++d) g = fmaf(x[d], e[d], g);
                float dd = __fadd_rn(__fsub_rn(A, __fmul_rn(2.0f, g)), Cw[k]);
                if (dd < bd) { bd = dd; win = k; }
            }
        }
        sWin[p] = win;
        out[OUT_IDX + n] = (float)win;
    }
    __syncthreads();

    // ---- epilogue: quantized NCHW + loss partial (plain store) -------------
    {
        const int pl = tid & 63, qtr = tid >> 6;
        const int win = sWin[pl];
        const int ch0 = qtr * 16;
        float q[16];
        const float4* q4 = (const float4*)(emb + (size_t)win * DDIM + ch0);
        #pragma unroll
        for (int j = 0; j < 4; ++j) ((float4*)q)[j] = q4[j];
        const size_t off = (size_t)b * DDIM * HW + (size_t)ch0 * HW + (hw0 + pl);
        const float* xin2 = inp + off;
        float* orow = out + off;
        float lacc = 0.f;
        #pragma unroll
        for (int j = 0; j < 16; ++j) {
            float xv = xin2[(size_t)j * HW];
            float diff = __fsub_rn(q[j], xv);
            orow[(size_t)j * HW] = __fadd_rn(xv, diff);   // ref's x + (q - x)
            lacc = fmaf(diff, diff, lacc);
        }
        #pragma unroll
        for (int o2 = 32; o2 > 0; o2 >>= 1) lacc += __shfl_down(lacc, o2, 64);
        if (lane == 0) sred[wave] = lacc;
    }
    __syncthreads();
    if (tid == 0)
        ws[WS_PART + blockIdx.x] = sred[0] + sred[1] + sred[2] + sred[3];
}

// 1 block x 256: reduce 1024 partials -> loss; write nll
__global__ __launch_bounds__(256) void vq_fin(const float* __restrict__ ws,
                                              float* __restrict__ out) {
    __shared__ float sred[4];
    const int tid = threadIdx.x;
    float s = 0.f;
    #pragma unroll
    for (int j = 0; j < 4; ++j) s += ws[WS_PART + j * 256 + tid];
    #pragma unroll
    for (int off = 32; off > 0; off >>= 1) s += __shfl_down(s, off, 64);
    if ((tid & 63) == 0) sred[tid >> 6] = s;
    __syncthreads();
    if (tid == 0) {
        float L = sred[0] + sred[1] + sred[2] + sred[3];
        out[OUT_LOSS] = L * (1.25f / 4194304.0f);   // (1+CC)*mean over N*D
        out[OUT_NLL]  = 1.0f;
    }
}

extern "C" void kernel_launch(void* const* d_in, const int* in_sizes, int n_in,
                              void* d_out, int out_size, void* d_ws, size_t ws_size,
                              hipStream_t stream) {
    const float* inp = (const float*)d_in[0];
    const float* emb = (const float*)d_in[1];
    float* out = (float*)d_out;
    float* ws  = (float*)d_ws;

    vq_init<<<16, 64, 0, stream>>>(emb, ws);
    vq_main<<<NBLK, 256, 0, stream>>>(inp, emb, ws, out);
    vq_fin<<<1, 256, 0, stream>>>(ws, out);
}

// Round 16
// 109.133 us; speedup vs baseline: 2.0065x; 1.1166x over previous
//
#include <hip/hip_runtime.h>
#include <stdint.h>

// VQ-VAE vector quantizer — fp32, NCHW input [64,64,32,32], emb [1024,64].
// r32 = R10 RESTORED byte-for-byte (109.4us session best; vq_main 47us).
// Final structure: 3 kernels (no device fence — R5 isolated its 32us cost);
// swapped-operand MFMA (D[code][point], R1/R6); per-lane u64 candidate
// lists with fixed-threshold branch (R6); 4-way wave-parallel rescue with
// ascending-k merge (R10, -4.4us). Falsified alternatives (kept for the
// record): occupancy+ (R8), tile shapes (R3/R9), LDS x-staging (R4), fused
// sweep w/ running threshold (R7: loop-carried dep kills pipelining),
// masked sweep-2 (R11 spill / R12 null: sweep MFMAs off critical path),
// depth-4 prefetch (R14 spill / R15 clean but -10us via occupancy loss:
// TLP already covers E-latency; per-wave ILP costs registers).
constexpr int KCODES = 1024;
constexpr int DDIM   = 64;
constexpr int HW     = 1024;
constexpr int NPTS   = 65536;
constexpr int PPB    = 64;            // points per block
constexpr int NBLK   = NPTS / PPB;    // 1024

constexpr int OUT_IDX  = 4194304;
constexpr int OUT_LOSS = 4259840;
constexpr int OUT_NLL  = 4259841;

// ws 32-bit-unit offsets
constexpr int WS_MAXC  = 0;       // 16 f  : per-init-block max C
constexpr int WS_C     = 16;      // 1024 f: exact np C_k
constexpr int WS_E     = 2048;    // 32768 u32: SWIZZLED bf16-E (64 chunks x 2KB)
constexpr int WS_PART  = 34816;   // 1024 f: per-block loss partials

typedef __attribute__((ext_vector_type(8))) short short8v;
typedef __attribute__((ext_vector_type(4))) float float4v;

__device__ __forceinline__ uint16_t f2bf(float f) {   // RNE fp32->bf16
    uint32_t u = __float_as_uint(f);
    return (uint16_t)((u + 0x7fffu + ((u >> 16) & 1u)) >> 16);
}
__device__ __forceinline__ uint32_t pack2bf(float a, float b) {
    return (uint32_t)f2bf(a) | ((uint32_t)f2bf(b) << 16);
}

__device__ __forceinline__ float np_pairwise_sumsq64(const float* a) {
    float r[8];
    #pragma unroll
    for (int j = 0; j < 8; ++j) r[j] = __fmul_rn(a[j], a[j]);
    #pragma unroll
    for (int i = 8; i < 64; i += 8)
        #pragma unroll
        for (int j = 0; j < 8; ++j)
            r[j] = __fadd_rn(r[j], __fmul_rn(a[i + j], a[i + j]));
    return __fadd_rn(__fadd_rn(__fadd_rn(r[0], r[1]), __fadd_rn(r[2], r[3])),
                     __fadd_rn(__fadd_rn(r[4], r[5]), __fadd_rn(r[6], r[7])));
}

// 16 blocks x 64 threads: code k = blockIdx*64 + tid. Writes SWIZZLED E.
__global__ __launch_bounds__(64) void vq_init(const float* __restrict__ emb,
                                              float* __restrict__ ws) {
    const int k = blockIdx.x * 64 + threadIdx.x;
    float row[DDIM];
    const float4* src = (const float4*)(emb + (size_t)k * DDIM);
    #pragma unroll
    for (int j = 0; j < 16; ++j) ((float4*)row)[j] = src[j];
    float C = np_pairwise_sumsq64(row);
    ws[WS_C + k] = C;
    {
        const int c = k >> 4, col = k & 15;
        uint32_t* eb = (uint32_t*)ws + WS_E + c * 512;   // chunk base (u32)
        #pragma unroll
        for (int q = 0; q < 4; ++q) {
            uint32_t* d0 = eb + (q * 16 + col) * 4;          // b0 plane
            uint32_t* d1 = eb + 256 + (q * 16 + col) * 4;    // b1 plane
            #pragma unroll
            for (int j = 0; j < 4; ++j) {
                d0[j] = pack2bf(row[q * 8 + 2 * j],      row[q * 8 + 2 * j + 1]);
                d1[j] = pack2bf(row[32 + q * 8 + 2 * j], row[32 + q * 8 + 2 * j + 1]);
            }
        }
    }
    float m = C;
    #pragma unroll
    for (int off = 32; off > 0; off >>= 1) m = fmaxf(m, __shfl_down(m, off, 64));
    if (threadIdx.x == 0) ws[WS_MAXC + blockIdx.x] = m;
}

__global__ __launch_bounds__(256, 4) void vq_main(
        const float* __restrict__ inp, const float* __restrict__ emb,
        float* __restrict__ ws, float* __restrict__ out)
{
    __shared__ float    sAp[PPB][4];    // pairwise partials (r2j + r2j+1)
    __shared__ float    sA[PPB];
    __shared__ float    sPart[4][PPB];
    __shared__ float    sThr[PPB];
    __shared__ unsigned long long sCandL[16][PPB];  // [wave*4+quad][point]
    __shared__ int      sCntL[16][PPB];
    __shared__ float    sResB[4][PPB];  // per-wave partial min distance
    __shared__ int      sResW[4][PPB];  // per-wave partial argmin
    __shared__ int      sWin[PPB];
    __shared__ float    sred[4];

    const int tid  = threadIdx.x;
    const int lane = tid & 63;
    const int wave = tid >> 6;          // = code quarter
    const int col  = lane & 15;         // = POINT within 16-group (swapped layout)
    const int quad = lane >> 4;         // = code sub-quad (rows quad*4+r)
    const int base = blockIdx.x * PPB;
    const int b    = base >> 10;
    const int hw0  = base & 1023;

    // ---- prologue: exact-A partials, 4 threads per point (bit-exact tree
    //      split of np pairwise: this thread computes r_{2j}+r_{2j+1}) -------
    {
        const int pp = tid >> 2;            // point
        const int jj = (tid & 3) * 2;       // r-pair base
        const float* xin = inp + (size_t)b * DDIM * HW + (hw0 + pp);
        float r0, r1;
        {
            float v0 = xin[(size_t)jj * HW];
            float v1 = xin[(size_t)(jj + 1) * HW];
            r0 = __fmul_rn(v0, v0);
            r1 = __fmul_rn(v1, v1);
        }
        #pragma unroll
        for (int i = 8; i < 64; i += 8) {
            float v0 = xin[(size_t)(i + jj) * HW];
            float v1 = xin[(size_t)(i + jj + 1) * HW];
            r0 = __fadd_rn(r0, __fmul_rn(v0, v0));
            r1 = __fadd_rn(r1, __fmul_rn(v1, v1));
        }
        sAp[pp][tid & 3] = __fadd_rn(r0, r1);
    }

    // ---- X-fragments for 4 row-groups (unchanged; reused as MFMA B-op) ----
    short8v a[4][2];
    #pragma unroll
    for (int g = 0; g < 4; ++g) {
        const float* xp = inp + (size_t)b * DDIM * HW + (hw0 + g * 16 + col);
        short8v t0, t1;
        #pragma unroll
        for (int j = 0; j < 8; ++j) {
            t0[j] = (short)f2bf(xp[(size_t)(quad * 8 + j) * HW]);
            t1[j] = (short)f2bf(xp[(size_t)(32 + quad * 8 + j) * HW]);
        }
        a[g][0] = t0; a[g][1] = t1;
    }

    // swizzled E: lane reads its 16B at chunk*2048 + plane*1024 + lane*16 —
    // contiguous 1KB per wave-load; lane&15 indexes CODE -> valid A-fragment.
    const char* Eb = (const char*)((const uint32_t*)ws + WS_E);
    const char* Ew = Eb + (size_t)wave * 16 * 2048 + (size_t)lane * 16;
    const float* Cw = ws + WS_C;
    const int k0 = wave * 256;
    const float4v* Cq = (const float4v*)(ws + WS_C + k0);   // 16B-aligned

    // ---- sweep 1: per-point score-max, per-lane (no shuffles in loop) -----
    float gmax[4] = {-3.0e38f, -3.0e38f, -3.0e38f, -3.0e38f};
    {
        short8v pa0 = *(const short8v*)(Ew);
        short8v pa1 = *(const short8v*)(Ew + 1024);
        short8v pb0 = *(const short8v*)(Ew + 2048);
        short8v pb1 = *(const short8v*)(Ew + 3072);
        float4v ca4 = Cq[quad];
        float4v cb4 = Cq[4 + quad];
        #pragma unroll 1
        for (int c2 = 0; c2 < 16; c2 += 2) {
            short8v u0 = pa0, u1 = pa1; float4v uc4 = ca4;
            if (c2 + 2 < 16) {
                const char* er = Ew + (size_t)(c2 + 2) * 2048;
                pa0 = *(const short8v*)(er);
                pa1 = *(const short8v*)(er + 1024);
                ca4 = Cq[(c2 + 2) * 4 + quad];
            }
            {
                float4v ci = {uc4[0] * -0.5f, uc4[1] * -0.5f,
                              uc4[2] * -0.5f, uc4[3] * -0.5f};
                #pragma unroll
                for (int g = 0; g < 4; ++g) {
                    float4v acc = ci;
                    acc = __builtin_amdgcn_mfma_f32_16x16x32_bf16(u0, a[g][0], acc, 0, 0, 0);
                    acc = __builtin_amdgcn_mfma_f32_16x16x32_bf16(u1, a[g][1], acc, 0, 0, 0);
                    gmax[g] = fmaxf(gmax[g],
                                    fmaxf(fmaxf(acc[0], acc[1]), fmaxf(acc[2], acc[3])));
                }
            }
            short8v v0 = pb0, v1 = pb1; float4v vc4 = cb4;
            if (c2 + 3 < 16) {
                const char* er = Ew + (size_t)(c2 + 3) * 2048;
                pb0 = *(const short8v*)(er);
                pb1 = *(const short8v*)(er + 1024);
                cb4 = Cq[(c2 + 3) * 4 + quad];
            }
            {
                float4v ci = {vc4[0] * -0.5f, vc4[1] * -0.5f,
                              vc4[2] * -0.5f, vc4[3] * -0.5f};
                #pragma unroll
                for (int g = 0; g < 4; ++g) {
                    float4v acc = ci;
                    acc = __builtin_amdgcn_mfma_f32_16x16x32_bf16(v0, a[g][0], acc, 0, 0, 0);
                    acc = __builtin_amdgcn_mfma_f32_16x16x32_bf16(v1, a[g][1], acc, 0, 0, 0);
                    gmax[g] = fmaxf(gmax[g],
                                    fmaxf(fmaxf(acc[0], acc[1]), fmaxf(acc[2], acc[3])));
                }
            }
        }
    }
    // cross-quad reduce: 2 shuffles
    #pragma unroll
    for (int g = 0; g < 4; ++g) {
        float m = gmax[g];
        m = fmaxf(m, __shfl_xor(m, 16, 64));
        m = fmaxf(m, __shfl_xor(m, 32, 64));
        if (quad == 0) sPart[wave][g * 16 + col] = m;
    }
    __syncthreads();

    // ---- per-point threshold (also combine exact-A partials, exact tree) ---
    if (tid < PPB) {
        float A = __fadd_rn(__fadd_rn(sAp[tid][0], sAp[tid][1]),
                            __fadd_rn(sAp[tid][2], sAp[tid][3]));
        sA[tid] = A;
        float gm = fmaxf(fmaxf(sPart[0][tid], sPart[1][tid]),
                         fmaxf(sPart[2][tid], sPart[3][tid]));
        float mc = ws[WS_MAXC];
        #pragma unroll
        for (int j = 1; j < 16; ++j) mc = fmaxf(mc, ws[WS_MAXC + j]);
        sThr[tid] = gm - (0.015625f * sqrtf(A) * sqrtf(mc) + 6e-5f);
    }
    __syncthreads();

    float thrg[4];
    #pragma unroll
    for (int g = 0; g < 4; ++g) thrg[g] = sThr[g * 16 + col];

    // ---- sweep 2: candidates via per-lane u64 register lists ---------------
    unsigned long long lst[4] = {0ull, 0ull, 0ull, 0ull};
    int cnt[4] = {0, 0, 0, 0};
    {
        short8v pa0 = *(const short8v*)(Ew);
        short8v pa1 = *(const short8v*)(Ew + 1024);
        short8v pb0 = *(const short8v*)(Ew + 2048);
        short8v pb1 = *(const short8v*)(Ew + 3072);
        float4v ca4 = Cq[quad];
        float4v cb4 = Cq[4 + quad];
        #pragma unroll 1
        for (int c2 = 0; c2 < 16; c2 += 2) {
            short8v u0 = pa0, u1 = pa1; float4v uc4 = ca4;
            if (c2 + 2 < 16) {
                const char* er = Ew + (size_t)(c2 + 2) * 2048;
                pa0 = *(const short8v*)(er);
                pa1 = *(const short8v*)(er + 1024);
                ca4 = Cq[(c2 + 2) * 4 + quad];
            }
            {
                float4v ci = {uc4[0] * -0.5f, uc4[1] * -0.5f,
                              uc4[2] * -0.5f, uc4[3] * -0.5f};
                const int kb = k0 + c2 * 16 + quad * 4;
                #pragma unroll
                for (int g = 0; g < 4; ++g) {
                    float4v acc = ci;
                    acc = __builtin_amdgcn_mfma_f32_16x16x32_bf16(u0, a[g][0], acc, 0, 0, 0);
                    acc = __builtin_amdgcn_mfma_f32_16x16x32_bf16(u1, a[g][1], acc, 0, 0, 0);
                    float m4 = fmaxf(fmaxf(acc[0], acc[1]), fmaxf(acc[2], acc[3]));
                    if (__any(m4 >= thrg[g])) {
                        #pragma unroll
                        for (int r = 0; r < 4; ++r) {
                            if (acc[r] >= thrg[g]) {
                                if (cnt[g] < 4)
                                    lst[g] |= (unsigned long long)(unsigned)(kb + r)
                                              << (cnt[g] << 4);
                                ++cnt[g];
                            }
                        }
                    }
                }
            }
            short8v v0 = pb0, v1 = pb1; float4v vc4 = cb4;
            if (c2 + 3 < 16) {
                const char* er = Ew + (size_t)(c2 + 3) * 2048;
                pb0 = *(const short8v*)(er);
                pb1 = *(const short8v*)(er + 1024);
                cb4 = Cq[(c2 + 3) * 4 + quad];
            }
            {
                float4v ci = {vc4[0] * -0.5f, vc4[1] * -0.5f,
                              vc4[2] * -0.5f, vc4[3] * -0.5f};
                const int kb = k0 + (c2 + 1) * 16 + quad * 4;
                #pragma unroll
                for (int g = 0; g < 4; ++g) {
                    float4v acc = ci;
                    acc = __builtin_amdgcn_mfma_f32_16x16x32_bf16(v0, a[g][0], acc, 0, 0, 0);
                    acc = __builtin_amdgcn_mfma_f32_16x16x32_bf16(v1, a[g][1], acc, 0, 0, 0);
                    float m4 = fmaxf(fmaxf(acc[0], acc[1]), fmaxf(acc[2], acc[3]));
                    if (__any(m4 >= thrg[g])) {
                        #pragma unroll
                        for (int r = 0; r < 4; ++r) {
                            if (acc[r] >= thrg[g]) {
                                if (cnt[g] < 4)
                                    lst[g] |= (unsigned long long)(unsigned)(kb + r)
                                              << (cnt[g] << 4);
                                ++cnt[g];
                            }
                        }
                    }
                }
            }
        }
    }
    {
        const int wq = wave * 4 + quad;
        #pragma unroll
        for (int g = 0; g < 4; ++g) {
            sCandL[wq][g * 16 + col] = lst[g];
            sCntL[wq][g * 16 + col]  = cnt[g];
        }
    }
    __syncthreads();

    // ---- rescue phase A: each wave exact-evals ITS candidate quads ---------
    //      (wq = 4*wave..4*wave+3, ascending disjoint k-ranges; identical
    //      per-candidate numerics to the R6 serial scan)
    {
        const int p = lane;
        int tot = 0, cmax = 0, mycnt = 0;
        #pragma unroll
        for (int wq = 0; wq < 16; ++wq) {
            int c = sCntL[wq][p];
            tot += c;
            cmax = c > cmax ? c : cmax;
            if ((wq >> 2) == wave) mycnt += c;
        }
        if (tot >= 2 && cmax <= 4) {
            float bd = 3.0e38f; int win = KCODES - 1;
            if (mycnt > 0) {
                const float* xin = inp + (size_t)b * DDIM * HW + (hw0 + p);
                float x[DDIM];
                #pragma unroll
                for (int d = 0; d < DDIM; ++d) x[d] = xin[(size_t)d * HW];
                const float A = sA[p];
                #pragma unroll 1
                for (int q = 0; q < 4; ++q) {
                    const int wq = wave * 4 + q;
                    int c = sCntL[wq][p];
                    unsigned long long L = sCandL[wq][p];
                    #pragma unroll 1
                    for (int i = 0; i < c; ++i) {       // ascending k order
                        int k = (int)(L & 0xffffu);
                        L >>= 16;
                        float e[DDIM];
                        const float4* e4 = (const float4*)(emb + (size_t)k * DDIM);
                        #pragma unroll
                        for (int j = 0; j < 16; ++j) ((float4*)e)[j] = e4[j];
                        float g = 0.f;
                        #pragma unroll
                        for (int d = 0; d < DDIM; ++d) g = fmaf(x[d], e[d], g);
                        float dd = __fadd_rn(__fsub_rn(A, __fmul_rn(2.0f, g)), Cw[k]);
                        if (dd < bd || (dd == bd && k < win)) { bd = dd; win = k; }
                    }
                }
            }
            sResB[wave][p] = bd;
            sResW[wave][p] = win;
        }
    }
    __syncthreads();

    // ---- rescue phase B: combine (tid<64); fast/fallback paths unchanged ---
    if (tid < PPB) {
        const int p = tid, n = base + p;
        int tot = 0, cmax = 0;
        #pragma unroll
        for (int wq = 0; wq < 16; ++wq) {
            int c = sCntL[wq][p];
            tot += c;
            cmax = c > cmax ? c : cmax;
        }
        int win;
        if (tot == 1) {
            win = 0;
            #pragma unroll
            for (int wq = 0; wq < 16; ++wq)
                if (sCntL[wq][p]) win = (int)(sCandL[wq][p] & 0xffffu);
        } else if (cmax <= 4) {
            float bd = 3.0e38f; win = KCODES - 1;
            #pragma unroll
            for (int w = 0; w < 4; ++w) {       // ascending k-range order
                float dw = sResB[w][p];
                int   ww = sResW[w][p];
                if (dw < bd || (dw == bd && ww < win)) { bd = dw; win = ww; }
            }
        } else {                                    // overflow safety
            const float* xin = inp + (size_t)b * DDIM * HW + (hw0 + p);
            float x[DDIM];
            #pragma unroll
            for (int d = 0; d < DDIM; ++d) x[d] = xin[(size_t)d * HW];
            const float A = sA[p];
            float bd = 3.0e38f; win = KCODES - 1;
            #pragma unroll 1
            for (int k = 0; k < KCODES; ++k) {
                float e[DDIM];
                const float4* e4 = (const float4*)(emb + (size_t)k * DDIM);
                #pragma unroll
                for (int j = 0; j < 16; ++j) ((float4*)e)[j] = e4[j];
                float g = 0.f;
                #pragma unroll
                for (int d = 0; d < DDIM; ++d) g = fmaf(x[d], e[d], g);
                float dd = __fadd_rn(__fsub_rn(A, __fmul_rn(2.0f, g)), Cw[k]);
                if (dd < bd) { bd = dd; win = k; }
            }
        }
        sWin[p] = win;
        out[OUT_IDX + n] = (float)win;
    }
    __syncthreads();

    // ---- epilogue: quantized NCHW + loss partial (plain store) -------------
    {
        const int pl = tid & 63, qtr = tid >> 6;
        const int win = sWin[pl];
        const int ch0 = qtr * 16;
        float q[16];
        const float4* q4 = (const float4*)(emb + (size_t)win * DDIM + ch0);
        #pragma unroll
        for (int j = 0; j < 4; ++j) ((float4*)q)[j] = q4[j];
        const size_t off = (size_t)b * DDIM * HW + (size_t)ch0 * HW + (hw0 + pl);
        const float* xin2 = inp + off;
        float* orow = out + off;
        float lacc = 0.f;
        #pragma unroll
        for (int j = 0; j < 16; ++j) {
            float xv = xin2[(size_t)j * HW];
            float diff = __fsub_rn(q[j], xv);
            orow[(size_t)j * HW] = __fadd_rn(xv, diff);   // ref's x + (q - x)
            lacc = fmaf(diff, diff, lacc);
        }
        #pragma unroll
        for (int o2 = 32; o2 > 0; o2 >>= 1) lacc += __shfl_down(lacc, o2, 64);
        if (lane == 0) sred[wave] = lacc;
    }
    __syncthreads();
    if (tid == 0)
        ws[WS_PART + blockIdx.x] = sred[0] + sred[1] + sred[2] + sred[3];
}

// 1 block x 256: reduce 1024 partials -> loss; write nll
__global__ __launch_bounds__(256) void vq_fin(const float* __restrict__ ws,
                                              float* __restrict__ out) {
    __shared__ float sred[4];
    const int tid = threadIdx.x;
    float s = 0.f;
    #pragma unroll
    for (int j = 0; j < 4; ++j) s += ws[WS_PART + j * 256 + tid];
    #pragma unroll
    for (int off = 32; off > 0; off >>= 1) s += __shfl_down(s, off, 64);
    if ((tid & 63) == 0) sred[tid >> 6] = s;
    __syncthreads();
    if (tid == 0) {
        float L = sred[0] + sred[1] + sred[2] + sred[3];
        out[OUT_LOSS] = L * (1.25f / 4194304.0f);   // (1+CC)*mean over N*D
        out[OUT_NLL]  = 1.0f;
    }
}

extern "C" void kernel_launch(void* const* d_in, const int* in_sizes, int n_in,
                              void* d_out, int out_size, void* d_ws, size_t ws_size,
                              hipStream_t stream) {
    const float* inp = (const float*)d_in[0];
    const float* emb = (const float*)d_in[1];
    float* out = (float*)d_out;
    float* ws  = (float*)d_ws;

    vq_init<<<16, 64, 0, stream>>>(emb, ws);
    vq_main<<<NBLK, 256, 0, stream>>>(inp, emb, ws, out);
    vq_fin<<<1, 256, 0, stream>>>(ws, out);
}